// Round 1
// baseline (12251.045 us; speedup 1.0000x reference)
//
#include <hip/hip_runtime.h>
#include <math.h>

#define SEQ 96
#define EMB 768
#define G4  3072   // 4*H
#define NLAYER 95  // conv layers

// ---------------- device-scope spin barrier (flags zeroed per call) -------
__device__ __forceinline__ void gbar(unsigned* flags, int nwg, unsigned target) {
    __threadfence();          // release all prior global writes (agent scope)
    __syncthreads();
    if (threadIdx.x == 0) {
        __hip_atomic_store(&flags[blockIdx.x], target,
                           __ATOMIC_RELEASE, __HIP_MEMORY_SCOPE_AGENT);
    }
    for (int i = threadIdx.x; i < nwg; i += blockDim.x) {
        while (__hip_atomic_load(&flags[i], __ATOMIC_ACQUIRE,
                                 __HIP_MEMORY_SCOPE_AGENT) < target) {
            __builtin_amdgcn_s_sleep(2);
        }
    }
    __threadfence();          // acquire: invalidate L1 before reading peers' data
    __syncthreads();
}

__device__ __forceinline__ float red16(float a) {
    a += __shfl_xor(a, 8, 16);
    a += __shfl_xor(a, 4, 16);
    a += __shfl_xor(a, 2, 16);
    a += __shfl_xor(a, 1, 16);
    return a;
}

__device__ __forceinline__ float sigmoidf_(float x) {
    return 1.0f / (1.0f + __expf(-x));
}

// ---------------- emb2 gather, col-major x0[col][e] -----------------------
__global__ void k_embed(const int* __restrict__ xids,
                        const float* __restrict__ emb2,
                        float* __restrict__ xA) {
    const int col = blockIdx.x;                 // 96 blocks
    const int tok = xids[col];
    for (int e = threadIdx.x; e < EMB; e += 256)
        xA[col * EMB + e] = emb2[(size_t)tok * EMB + e];
}

// ---------------- A1[t][row] = Wih1@emb1[x_t] + bih1 + bhh1 ---------------
__global__ __launch_bounds__(256) void k_a1(const int* __restrict__ xids,
                                            const float* __restrict__ emb1,
                                            const float* __restrict__ wih,
                                            const float* __restrict__ bih,
                                            const float* __restrict__ bhh,
                                            float* __restrict__ A1) {
    __shared__ float sx[EMB];
    const int tid = threadIdx.x;
    const int l16 = tid & 15;
    const int r16 = tid >> 4;
    const int row = blockIdx.x * 16 + r16;      // 192 blocks x 16 rows
    float w[48];
#pragma unroll
    for (int i = 0; i < 48; ++i)
        w[i] = wih[(size_t)row * EMB + l16 + (i << 4)];
    const float bsum = bih[row] + bhh[row];
    for (int t = 0; t < SEQ; ++t) {
        const int tok = xids[t];
        __syncthreads();
        for (int i = tid; i < EMB; i += 256)
            sx[i] = emb1[(size_t)tok * EMB + i];
        __syncthreads();
        float a = 0.f;
#pragma unroll
        for (int i = 0; i < 48; ++i)
            a = fmaf(w[i], sx[l16 + (i << 4)], a);
        a = red16(a);
        if (l16 == 0) A1[t * G4 + row] = a + bsum;
    }
}

// ---------------- persistent LSTM: 192 WGs, 97 ticks, skewed layers -------
__global__ __launch_bounds__(256, 1) void k_lstm(
    const float* __restrict__ hstate, const float* __restrict__ cstate,
    const float* __restrict__ wih, const float* __restrict__ whh,
    const float* __restrict__ bih, const float* __restrict__ bhh,
    const float* __restrict__ A1,
    float* __restrict__ h1buf, float* __restrict__ h2buf,
    unsigned* __restrict__ flags, float* __restrict__ dout) {

    __shared__ float hx[EMB];     // h1(T-1): layer1 h-prev AND layer2 input
    __shared__ float hb2[EMB];    // h2(T-2)
    __shared__ float g1s[16], g2s[16];
    __shared__ float c1s[4], c2s[4];

    const int tid  = threadIdx.x;
    const int l16  = tid & 15;
    const int r16  = tid >> 4;            // 0..15 -> (gate = r16>>2, jl = r16&3)
    const int gate = r16 >> 2;
    const int jl   = r16 & 3;
    const int j0   = blockIdx.x * 4;      // 192 WGs x 4 h-indices
    const int grow = gate * EMB + j0 + jl;

    // register-resident weight slices
    float wh1r[48], wi2r[48], wh2r[48];
    const float* whh1 = whh;
    const float* wih2 = wih + (size_t)G4 * EMB;
    const float* whh2 = whh + (size_t)G4 * EMB;
#pragma unroll
    for (int i = 0; i < 48; ++i) {
        const int k = l16 + (i << 4);
        wh1r[i] = whh1[(size_t)grow * EMB + k];
        wi2r[i] = wih2[(size_t)grow * EMB + k];
        wh2r[i] = whh2[(size_t)grow * EMB + k];
    }
    const float b2 = bih[G4 + grow] + bhh[G4 + grow];

    if (tid < 4)                c1s[tid]     = cstate[j0 + tid];
    else if (tid < 8)           c2s[tid - 4] = cstate[EMB + j0 + (tid - 4)];
    __syncthreads();

    for (int T = 0; T <= SEQ; ++T) {
        for (int i = tid; i < EMB; i += 256) {
            hx[i] = (T == 0) ? hstate[i] : h1buf[(T - 1) * EMB + i];
            if (T >= 1)
                hb2[i] = (T == 1) ? hstate[EMB + i] : h2buf[(T - 2) * EMB + i];
        }
        __syncthreads();

        if (T < SEQ) {           // layer 1, step T
            float a = 0.f;
#pragma unroll
            for (int i = 0; i < 48; ++i)
                a = fmaf(wh1r[i], hx[l16 + (i << 4)], a);
            a = red16(a);
            if (l16 == 0) g1s[r16] = a + A1[T * G4 + grow];
        }
        if (T >= 1) {            // layer 2, step T-1
            float b = 0.f;
#pragma unroll
            for (int i = 0; i < 48; ++i)
                b = fmaf(wi2r[i], hx[l16 + (i << 4)], b);
#pragma unroll
            for (int i = 0; i < 48; ++i)
                b = fmaf(wh2r[i], hb2[l16 + (i << 4)], b);
            b = red16(b);
            if (l16 == 0) g2s[r16] = b + b2;
        }
        __syncthreads();

        if (tid < 4 && T < SEQ) {
            const int j = tid;
            const float i_ = sigmoidf_(g1s[j]);
            const float f_ = sigmoidf_(g1s[4 + j]);
            const float g_ = tanhf(g1s[8 + j]);
            const float o_ = sigmoidf_(g1s[12 + j]);
            const float c  = f_ * c1s[j] + i_ * g_;
            c1s[j] = c;
            const float h = o_ * tanhf(c);
            h1buf[T * EMB + j0 + j] = h;
            if (T == SEQ - 1) {
                dout[1 + j0 + j]    = h;   // h[0]
                dout[1537 + j0 + j] = c;   // c[0]
            }
        } else if (tid >= 4 && tid < 8 && T >= 1) {
            const int j = tid - 4;
            const int s = T - 1;
            const float i_ = sigmoidf_(g2s[j]);
            const float f_ = sigmoidf_(g2s[4 + j]);
            const float g_ = tanhf(g2s[8 + j]);
            const float o_ = sigmoidf_(g2s[12 + j]);
            const float c  = f_ * c2s[j] + i_ * g_;
            c2s[j] = c;
            const float h = o_ * tanhf(c);
            h2buf[s * EMB + j0 + j] = h;
            if (s == SEQ - 1) {
                dout[1 + EMB + j0 + j]    = h;   // h[1]
                dout[1537 + EMB + j0 + j] = c;   // c[1]
            }
        }
        gbar(flags, 192, (unsigned)(T + 1));
    }
}

// ---------------- persistent conv stack: 256 WGs x 3 rows, 95 layers ------
__global__ __launch_bounds__(256, 1) void k_conv(
    const float* __restrict__ conv_w, const float* __restrict__ conv_b,
    float* __restrict__ xA, float* __restrict__ xB,
    unsigned* __restrict__ flags, float* __restrict__ dout) {

    __shared__ float ws[3 * EMB * 2];      // [row][k][{w0,w1}]
    __shared__ float xs[96 * 100];         // col-major staged chunk, pad 100

    const int tid = threadIdx.x;
    const int wg  = blockIdx.x;
    const int r0  = wg * 3;
    const int kq  = tid >> 5;              // 0..7: k-subrange within chunk
    const int cl  = tid & 31;

    for (int l = 0; l < NLAYER; ++l) {
        const int ncols = NLAYER - l;      // 95 .. 1 (column-cone pruning)
        const float* src = (l & 1) ? xB : xA;
        float*       dst = (l & 1) ? xA : xB;

        // stage this WG's 3 weight rows (coalesced float4)
        {
            const float4* wsrc =
                (const float4*)(conv_w + (size_t)l * (EMB * EMB * 2)
                                        + (size_t)r0 * (EMB * 2));
            float4* wdst = (float4*)ws;
            for (int i = tid; i < 1152; i += 256) wdst[i] = wsrc[i];
        }

        float acc[3][3];
#pragma unroll
        for (int r = 0; r < 3; ++r)
#pragma unroll
            for (int c = 0; c < 3; ++c) acc[r][c] = 0.f;

        const int scols = ncols + 1;       // need cols 0..ncols (roll)
        for (int ch = 0; ch < 8; ++ch) {
            const int k0 = ch * 96;
            __syncthreads();
            for (int i = tid; i < scols * 96; i += 256) {
                const int c  = i / 96;
                const int kk = i - c * 96;
                xs[c * 100 + kk] = src[c * EMB + k0 + kk];
            }
            __syncthreads();
            const int kb = kq * 12;
            for (int kk = 0; kk < 12; kk += 4) {
                const int kg = k0 + kb + kk;   // global k (weights)
                const int kl = kb + kk;        // k within chunk (xs)
                float4 wa[3], wb[3];
#pragma unroll
                for (int r = 0; r < 3; ++r) {
                    const float* wp = &ws[(r * EMB + kg) * 2];
                    wa[r] = *(const float4*)wp;
                    wb[r] = *(const float4*)(wp + 4);
                }
#pragma unroll
                for (int c3 = 0; c3 < 3; ++c3) {
                    const int col = cl + 32 * c3;
                    if (col < ncols) {
                        const float4 xv = *(const float4*)&xs[col * 100 + kl];
                        const float4 xr = *(const float4*)&xs[(col + 1) * 100 + kl];
#pragma unroll
                        for (int r = 0; r < 3; ++r) {
                            acc[r][c3] += wa[r].x * xv.x + wa[r].y * xr.x
                                        + wa[r].z * xv.y + wa[r].w * xr.y
                                        + wb[r].x * xv.z + wb[r].y * xr.z
                                        + wb[r].z * xv.w + wb[r].w * xr.w;
                        }
                    }
                }
            }
        }

        // reduce partials across the 8 kq groups (fixed order: deterministic)
        __syncthreads();
        float* part = xs;                  // alias staged buffer
#pragma unroll
        for (int r = 0; r < 3; ++r)
#pragma unroll
            for (int c3 = 0; c3 < 3; ++c3)
                part[(kq * 3 + r) * 96 + cl + 32 * c3] = acc[r][c3];
        __syncthreads();
#pragma unroll
        for (int r = 0; r < 3; ++r) {
            for (int col = tid; col < ncols; col += 256) {
                float s = 0.f;
#pragma unroll
                for (int q = 0; q < 8; ++q) s += part[(q * 3 + r) * 96 + col];
                s += conv_b[l * EMB + r0 + r];
                s = fmaxf(s, 0.f);
                dst[col * EMB + r0 + r] = s;
                if (l == NLAYER - 1)       // ncols==1 -> col==0: model2out
                    dout[3074 + r0 + r] = s;
            }
        }
        gbar(flags, 256, (unsigned)(l + 1));
    }
}

// ---------------- deterministic scalar epilogue ---------------------------
__global__ void k_final(const float* __restrict__ pred_w,
                        const float* __restrict__ pred_b,
                        const float* __restrict__ m2w,
                        const float* __restrict__ m2b,
                        const float* __restrict__ prev,
                        float* __restrict__ dout) {
    __shared__ float red[256];
    const int tid = threadIdx.x;
    float p1 = 0.f;
    for (int idx = tid; idx < 2 * EMB; idx += 256) {
        const int l = idx / EMB;
        const int j = idx - l * EMB;
        p1 += dout[1537 + idx] * pred_w[j * 2 + l];   // feat = c.T interleave
    }
    float p2 = 0.f;
    for (int e = tid; e < EMB; e += 256)
        p2 += dout[3074 + e] * m2w[2 * e] + prev[e] * m2w[2 * e + 1];

    red[tid] = p1;
    __syncthreads();
    for (int s = 128; s > 0; s >>= 1) {
        if (tid < s) red[tid] += red[tid + s];
        __syncthreads();
    }
    if (tid == 0) dout[0] = red[0] + pred_b[0];
    __syncthreads();
    red[tid] = p2;
    __syncthreads();
    for (int s = 128; s > 0; s >>= 1) {
        if (tid < s) red[tid] += red[tid + s];
        __syncthreads();
    }
    if (tid == 0) dout[3073] = red[0] + m2b[0];
}

extern "C" void kernel_launch(void* const* d_in, const int* in_sizes, int n_in,
                              void* d_out, int out_size, void* d_ws, size_t ws_size,
                              hipStream_t stream) {
    const int*   x      = (const int*)d_in[0];
    const float* hstate = (const float*)d_in[1];
    const float* cstate = (const float*)d_in[2];
    const float* prev   = (const float*)d_in[3];
    const float* emb1   = (const float*)d_in[4];
    const float* emb2   = (const float*)d_in[5];
    const float* wih    = (const float*)d_in[6];
    const float* whh    = (const float*)d_in[7];
    const float* bih    = (const float*)d_in[8];
    const float* bhh    = (const float*)d_in[9];
    const float* predw  = (const float*)d_in[10];
    const float* predb  = (const float*)d_in[11];
    const float* convw  = (const float*)d_in[12];
    const float* convb  = (const float*)d_in[13];
    const float* m2w    = (const float*)d_in[14];
    const float* m2b    = (const float*)d_in[15];
    float* out = (float*)d_out;

    unsigned* lstm_flags = (unsigned*)d_ws;          // 192 used (256 reserved)
    unsigned* conv_flags = lstm_flags + 256;         // 256
    float* base  = (float*)d_ws;
    float* A1    = base + 1024;                      // 96*3072
    float* h1buf = A1 + SEQ * G4;                    // 96*768
    float* h2buf = h1buf + SEQ * EMB;                // 96*768
    float* xA    = h2buf + SEQ * EMB;                // 96*768 (col-major)
    float* xB    = xA + SEQ * EMB;                   // 96*768

    hipMemsetAsync(d_ws, 0, 4096, stream);                       // flags
    hipMemsetAsync(d_out, 0, out_size * sizeof(float), stream);

    k_embed<<<96, 256, 0, stream>>>(x, emb2, xA);
    k_a1<<<192, 256, 0, stream>>>(x, emb1, wih, bih, bhh, A1);
    k_conv<<<256, 256, 0, stream>>>(convw, convb, xA, xB, conv_flags, out);
    k_lstm<<<192, 256, 0, stream>>>(hstate, cstate, wih, whh, bih, bhh,
                                    A1, h1buf, h2buf, lstm_flags, out);
    k_final<<<1, 256, 0, stream>>>(predw, predb, m2w, m2b, prev, out);
}

// Round 2
// 9261.337 us; speedup vs baseline: 1.3228x; 1.3228x over previous
//
#include <hip/hip_runtime.h>
#include <math.h>

#define SEQ 96
#define EMB 768
#define G4  3072   // 4*H
#define NLAYER 95  // conv layers
#define CPAD 100   // xs column pad (stride 100 floats -> 4-way LDS conflict max)

// ---------------- device-scope spin barrier (flags zeroed per call) -------
// wave 0 spins (relaxed); acquire fence after. All prior writes released by
// per-thread threadfence before the flag store.
__device__ __forceinline__ void gbar(unsigned* flags, int nwg, unsigned target) {
    __threadfence();          // release this thread's global writes (agent)
    __syncthreads();
    if (threadIdx.x == 0) {
        __hip_atomic_store(&flags[blockIdx.x], target,
                           __ATOMIC_RELEASE, __HIP_MEMORY_SCOPE_AGENT);
    }
    if (threadIdx.x < 64) {
        for (int i = threadIdx.x; i < nwg; i += 64) {
            while (__hip_atomic_load(&flags[i], __ATOMIC_RELAXED,
                                     __HIP_MEMORY_SCOPE_AGENT) < target) {
                __builtin_amdgcn_s_sleep(1);
            }
        }
    }
    __threadfence();          // acquire: make peers' writes visible
    __syncthreads();
}

__device__ __forceinline__ float red16(float a) {
    a += __shfl_xor(a, 8, 16);
    a += __shfl_xor(a, 4, 16);
    a += __shfl_xor(a, 2, 16);
    a += __shfl_xor(a, 1, 16);
    return a;
}

__device__ __forceinline__ float sigmoidf_(float x) {
    return 1.0f / (1.0f + __expf(-x));
}

// ---------------- emb2 gather, col-major x0[col][e] -----------------------
__global__ void k_embed(const int* __restrict__ xids,
                        const float* __restrict__ emb2,
                        float* __restrict__ xA) {
    const int col = blockIdx.x;                 // 96 blocks
    const int tok = xids[col];
    const int tid = threadIdx.x;
    if (tid < 192) {
        float4 v = *(const float4*)(emb2 + (size_t)tok * EMB + tid * 4);
        *(float4*)(xA + col * EMB + tid * 4) = v;
    }
}

// ---------------- A1[t][row] = Wih1@emb1[x_t] + bih1 + bhh1 ---------------
__global__ __launch_bounds__(256) void k_a1(const int* __restrict__ xids,
                                            const float* __restrict__ emb1,
                                            const float* __restrict__ wih,
                                            const float* __restrict__ bih,
                                            const float* __restrict__ bhh,
                                            float* __restrict__ A1) {
    __shared__ float sx[EMB];
    const int tid = threadIdx.x;
    const int l16 = tid & 15;
    const int r16 = tid >> 4;
    const int row = blockIdx.x * 16 + r16;      // 192 blocks x 16 rows
    float w[48];
#pragma unroll
    for (int i = 0; i < 48; ++i)
        w[i] = wih[(size_t)row * EMB + l16 + (i << 4)];
    const float bsum = bih[row] + bhh[row];
    for (int t = 0; t < SEQ; ++t) {
        const int tok = xids[t];
        __syncthreads();
        if (tid < 192) {
            float4 v = *(const float4*)(emb1 + (size_t)tok * EMB + tid * 4);
            *(float4*)(sx + tid * 4) = v;
        }
        __syncthreads();
        float a = 0.f;
#pragma unroll
        for (int i = 0; i < 48; ++i)
            a = fmaf(w[i], sx[l16 + (i << 4)], a);
        a = red16(a);
        if (l16 == 0) A1[t * G4 + row] = a + bsum;
    }
}

// ---------------- persistent LSTM: 192 WGs, 97 ticks, skewed layers -------
__global__ __launch_bounds__(256, 1) void k_lstm(
    const float* __restrict__ hstate, const float* __restrict__ cstate,
    const float* __restrict__ wih, const float* __restrict__ whh,
    const float* __restrict__ bih, const float* __restrict__ bhh,
    const float* __restrict__ A1,
    float* __restrict__ h1buf, float* __restrict__ h2buf,
    unsigned* __restrict__ flags, float* __restrict__ dout) {

    __shared__ float hx[EMB];     // h1(T-1): layer1 h-prev AND layer2 input
    __shared__ float hb2[EMB];    // h2(T-2)
    __shared__ float g1s[16], g2s[16];
    __shared__ float c1s[4], c2s[4];

    const int tid  = threadIdx.x;
    const int l16  = tid & 15;
    const int r16  = tid >> 4;            // 0..15 -> (gate = r16>>2, jl = r16&3)
    const int gate = r16 >> 2;
    const int jl   = r16 & 3;
    const int j0   = blockIdx.x * 4;      // 192 WGs x 4 h-indices
    const int grow = gate * EMB + j0 + jl;

    // register-resident weight slices
    float wh1r[48], wi2r[48], wh2r[48];
    const float* whh1 = whh;
    const float* wih2 = wih + (size_t)G4 * EMB;
    const float* whh2 = whh + (size_t)G4 * EMB;
#pragma unroll
    for (int i = 0; i < 48; ++i) {
        const int k = l16 + (i << 4);
        wh1r[i] = whh1[(size_t)grow * EMB + k];
        wi2r[i] = wih2[(size_t)grow * EMB + k];
        wh2r[i] = whh2[(size_t)grow * EMB + k];
    }
    const float b2 = bih[G4 + grow] + bhh[G4 + grow];

    if (tid < 4)                c1s[tid]     = cstate[j0 + tid];
    else if (tid < 8)           c2s[tid - 4] = cstate[EMB + j0 + (tid - 4)];
    __syncthreads();

    for (int T = 0; T <= SEQ; ++T) {
        if (tid < 192) {
            float4 hv = (T == 0)
                ? *(const float4*)(hstate + tid * 4)
                : *(const float4*)(h1buf + (T - 1) * EMB + tid * 4);
            float4 h2v = make_float4(0.f, 0.f, 0.f, 0.f);
            if (T >= 1)
                h2v = (T == 1)
                    ? *(const float4*)(hstate + EMB + tid * 4)
                    : *(const float4*)(h2buf + (T - 2) * EMB + tid * 4);
            *(float4*)(hx + tid * 4)  = hv;
            *(float4*)(hb2 + tid * 4) = h2v;
        }
        __syncthreads();

        if (T < SEQ) {           // layer 1, step T
            float a = 0.f;
#pragma unroll
            for (int i = 0; i < 48; ++i)
                a = fmaf(wh1r[i], hx[l16 + (i << 4)], a);
            a = red16(a);
            if (l16 == 0) g1s[r16] = a + A1[T * G4 + grow];
        }
        if (T >= 1) {            // layer 2, step T-1
            float b = 0.f;
#pragma unroll
            for (int i = 0; i < 48; ++i)
                b = fmaf(wi2r[i], hx[l16 + (i << 4)], b);
#pragma unroll
            for (int i = 0; i < 48; ++i)
                b = fmaf(wh2r[i], hb2[l16 + (i << 4)], b);
            b = red16(b);
            if (l16 == 0) g2s[r16] = b + b2;
        }
        __syncthreads();

        if (tid < 4 && T < SEQ) {
            const int j = tid;
            const float i_ = sigmoidf_(g1s[j]);
            const float f_ = sigmoidf_(g1s[4 + j]);
            const float g_ = tanhf(g1s[8 + j]);
            const float o_ = sigmoidf_(g1s[12 + j]);
            const float c  = f_ * c1s[j] + i_ * g_;
            c1s[j] = c;
            const float h = o_ * tanhf(c);
            h1buf[T * EMB + j0 + j] = h;
            if (T == SEQ - 1) {
                dout[1 + j0 + j]    = h;   // h[0]
                dout[1537 + j0 + j] = c;   // c[0]
            }
        } else if (tid >= 4 && tid < 8 && T >= 1) {
            const int j = tid - 4;
            const int s = T - 1;
            const float i_ = sigmoidf_(g2s[j]);
            const float f_ = sigmoidf_(g2s[4 + j]);
            const float g_ = tanhf(g2s[8 + j]);
            const float o_ = sigmoidf_(g2s[12 + j]);
            const float c  = f_ * c2s[j] + i_ * g_;
            c2s[j] = c;
            const float h = o_ * tanhf(c);
            h2buf[s * EMB + j0 + j] = h;
            if (s == SEQ - 1) {
                dout[1 + EMB + j0 + j]    = h;   // h[1]
                dout[1537 + EMB + j0 + j] = c;   // c[1]
            }
        }
        gbar(flags, 192, (unsigned)(T + 1));
    }
}

// ---------------- persistent conv stack: 256 WGs x 3 rows, 95 layers ------
// v2: weight prefetch 1 layer ahead (regs), pipelined chunk staging
// (issue ch+1 loads before computing ch), div-free float4 addressing.
__global__ __launch_bounds__(256, 1) void k_conv(
    const float* __restrict__ conv_w, const float* __restrict__ conv_b,
    float* __restrict__ xA, float* __restrict__ xB,
    unsigned* __restrict__ flags, float* __restrict__ dout) {

    __shared__ float ws[3 * EMB * 2];      // 18432 B: [row][k][{w0,w1}]
    __shared__ float xs[SEQ * CPAD];       // 38400 B: col-major staged chunk

    const int tid = threadIdx.x;
    const int wg  = blockIdx.x;
    const int r0  = wg * 3;
    const int kq  = tid >> 5;              // 0..7: k-subrange within chunk
    const int cl  = tid & 31;

    // --- precomputed staging map: float4 #fidx -> (col, quad) -------------
    int sc[9], sg[9], sl[9];               // col, global f4-offset, lds f4-off
#pragma unroll
    for (int j = 0; j < 9; ++j) {
        const int fidx = tid + j * 256;    // < 2304
        const int c = (fidx * 2731) >> 16; // fidx / 24 (exact for fidx<2304)
        const int q = fidx - c * 24;
        sc[j] = c;
        sg[j] = c * (EMB / 4) + q;         // float4 index into src column
        sl[j] = c * (CPAD / 4) + q;        // float4 index into xs
    }

    // --- weight slab map: 1152 float4 over 256 threads (<=5 each) ---------
    int wi[5];
#pragma unroll
    for (int j = 0; j < 5; ++j) wi[j] = tid + j * 256;

    // preload layer-0 weights into registers
    float4 wreg[5];
    {
        const float4* wsrc = (const float4*)(conv_w + (size_t)r0 * (EMB * 2));
#pragma unroll
        for (int j = 0; j < 5; ++j)
            if (wi[j] < 1152) wreg[j] = wsrc[wi[j]];
    }

    float4 R[9];                           // staged x chunk in flight

    for (int l = 0; l < NLAYER; ++l) {
        const int ncols = NLAYER - l;      // 95 .. 1 (column-cone pruning)
        const int scols = ncols + 1;       // need cols 0..ncols (roll)
        const float* src = (l & 1) ? xB : xA;
        float*       dst = (l & 1) ? xA : xB;
        const float4* src4 = (const float4*)src;

        // issue chunk-0 x loads ASAP (latency hides under ws write+sync)
#pragma unroll
        for (int j = 0; j < 9; ++j)
            if (sc[j] < scols) R[j] = src4[sg[j]];

        // commit prefetched weights to LDS
        {
            float4* wdst = (float4*)ws;
#pragma unroll
            for (int j = 0; j < 5; ++j)
                if (wi[j] < 1152) wdst[wi[j]] = wreg[j];
        }
        __syncthreads();                   // ws (and xs-free) ready

        float acc[3][3];
#pragma unroll
        for (int r = 0; r < 3; ++r)
#pragma unroll
            for (int c = 0; c < 3; ++c) acc[r][c] = 0.f;

        for (int ch = 0; ch < 8; ++ch) {
            if (ch) __syncthreads();       // prev chunk compute done
            // write staged regs -> xs
#pragma unroll
            for (int j = 0; j < 9; ++j)
                if (sc[j] < scols) ((float4*)xs)[sl[j]] = R[j];
            __syncthreads();               // xs ready
            // issue next chunk's loads (or next layer's weights) now;
            // latency overlaps with this chunk's compute
            if (ch < 7) {
                const int koff = (ch + 1) * 24;   // float4s per column step
#pragma unroll
                for (int j = 0; j < 9; ++j)
                    if (sc[j] < scols) R[j] = src4[sg[j] + koff];
            } else if (l + 1 < NLAYER) {
                const float4* wsrc = (const float4*)(conv_w
                        + (size_t)(l + 1) * (EMB * EMB * 2)
                        + (size_t)r0 * (EMB * 2));
#pragma unroll
                for (int j = 0; j < 5; ++j)
                    if (wi[j] < 1152) wreg[j] = wsrc[wi[j]];
            }

            const int kb = kq * 12;
#pragma unroll
            for (int kk = 0; kk < 12; kk += 4) {
                const int kg = ch * 96 + kb + kk;  // global k (weights)
                const int kl = kb + kk;            // k within chunk (xs)
                float4 wa[3], wb[3];
#pragma unroll
                for (int r = 0; r < 3; ++r) {
                    const float* wp = &ws[(r * EMB + kg) * 2];
                    wa[r] = *(const float4*)wp;
                    wb[r] = *(const float4*)(wp + 4);
                }
#pragma unroll
                for (int c3 = 0; c3 < 3; ++c3) {
                    const int col = cl + 32 * c3;
                    if (col < ncols) {
                        const float4 xv = *(const float4*)&xs[col * CPAD + kl];
                        const float4 xr = *(const float4*)&xs[(col + 1) * CPAD + kl];
#pragma unroll
                        for (int r = 0; r < 3; ++r) {
                            acc[r][c3] += wa[r].x * xv.x + wa[r].y * xr.x
                                        + wa[r].z * xv.y + wa[r].w * xr.y
                                        + wb[r].x * xv.z + wb[r].y * xr.z
                                        + wb[r].z * xv.w + wb[r].w * xr.w;
                        }
                    }
                }
            }
        }

        // reduce partials across the 8 kq groups (fixed order: deterministic)
        __syncthreads();
        float* part = xs;                  // alias staged buffer
#pragma unroll
        for (int r = 0; r < 3; ++r)
#pragma unroll
            for (int c3 = 0; c3 < 3; ++c3)
                part[(kq * 3 + r) * 96 + cl + 32 * c3] = acc[r][c3];
        __syncthreads();
#pragma unroll
        for (int r = 0; r < 3; ++r) {
            for (int col = tid; col < ncols; col += 256) {
                float s = 0.f;
#pragma unroll
                for (int q = 0; q < 8; ++q) s += part[(q * 3 + r) * 96 + col];
                s += conv_b[l * EMB + r0 + r];
                s = fmaxf(s, 0.f);
                dst[col * EMB + r0 + r] = s;
                if (l == NLAYER - 1)       // ncols==1 -> col==0: model2out
                    dout[3074 + r0 + r] = s;
            }
        }
        gbar(flags, 256, (unsigned)(l + 1));
    }
}

// ---------------- deterministic scalar epilogue ---------------------------
__global__ void k_final(const float* __restrict__ pred_w,
                        const float* __restrict__ pred_b,
                        const float* __restrict__ m2w,
                        const float* __restrict__ m2b,
                        const float* __restrict__ prev,
                        float* __restrict__ dout) {
    __shared__ float red[256];
    const int tid = threadIdx.x;
    float p1 = 0.f;
    for (int idx = tid; idx < 2 * EMB; idx += 256) {
        const int l = idx / EMB;
        const int j = idx - l * EMB;
        p1 += dout[1537 + idx] * pred_w[j * 2 + l];   // feat = c.T interleave
    }
    float p2 = 0.f;
    for (int e = tid; e < EMB; e += 256)
        p2 += dout[3074 + e] * m2w[2 * e] + prev[e] * m2w[2 * e + 1];

    red[tid] = p1;
    __syncthreads();
    for (int s = 128; s > 0; s >>= 1) {
        if (tid < s) red[tid] += red[tid + s];
        __syncthreads();
    }
    if (tid == 0) dout[0] = red[0] + pred_b[0];
    __syncthreads();
    red[tid] = p2;
    __syncthreads();
    for (int s = 128; s > 0; s >>= 1) {
        if (tid < s) red[tid] += red[tid + s];
        __syncthreads();
    }
    if (tid == 0) dout[3073] = red[0] + m2b[0];
}

extern "C" void kernel_launch(void* const* d_in, const int* in_sizes, int n_in,
                              void* d_out, int out_size, void* d_ws, size_t ws_size,
                              hipStream_t stream) {
    const int*   x      = (const int*)d_in[0];
    const float* hstate = (const float*)d_in[1];
    const float* cstate = (const float*)d_in[2];
    const float* prev   = (const float*)d_in[3];
    const float* emb1   = (const float*)d_in[4];
    const float* emb2   = (const float*)d_in[5];
    const float* wih    = (const float*)d_in[6];
    const float* whh    = (const float*)d_in[7];
    const float* bih    = (const float*)d_in[8];
    const float* bhh    = (const float*)d_in[9];
    const float* predw  = (const float*)d_in[10];
    const float* predb  = (const float*)d_in[11];
    const float* convw  = (const float*)d_in[12];
    const float* convb  = (const float*)d_in[13];
    const float* m2w    = (const float*)d_in[14];
    const float* m2b    = (const float*)d_in[15];
    float* out = (float*)d_out;

    unsigned* lstm_flags = (unsigned*)d_ws;          // 192 used (256 reserved)
    unsigned* conv_flags = lstm_flags + 256;         // 256
    float* base  = (float*)d_ws;
    float* A1    = base + 1024;                      // 96*3072
    float* h1buf = A1 + SEQ * G4;                    // 96*768
    float* h2buf = h1buf + SEQ * EMB;                // 96*768
    float* xA    = h2buf + SEQ * EMB;                // 96*768 (col-major)
    float* xB    = xA + SEQ * EMB;                   // 96*768

    hipMemsetAsync(d_ws, 0, 4096, stream);                       // flags
    hipMemsetAsync(d_out, 0, out_size * sizeof(float), stream);

    k_embed<<<96, 256, 0, stream>>>(x, emb2, xA);
    k_a1<<<192, 256, 0, stream>>>(x, emb1, wih, bih, bhh, A1);
    k_conv<<<256, 256, 0, stream>>>(convw, convb, xA, xB, conv_flags, out);
    k_lstm<<<192, 256, 0, stream>>>(hstate, cstate, wih, whh, bih, bhh,
                                    A1, h1buf, h2buf, lstm_flags, out);
    k_final<<<1, 256, 0, stream>>>(predw, predb, m2w, m2b, prev, out);
}

// Round 4
// 4557.848 us; speedup vs baseline: 2.6879x; 2.0320x over previous
//
#include <hip/hip_runtime.h>
#include <math.h>

#define SEQ 96
#define EMB 768
#define G4  3072   // 4*H
#define NLAYER 95  // conv layers
#define CKP 264    // xs col pitch (bf16 elems): 256 k-chunk + 8 pad
#define CONV_WG 48
#define LSTM_WG 192
#define XPITCH 1536  // ushorts per col in x buffers: 48 blocks x (hi16|lo16)

typedef float  f32x4  __attribute__((ext_vector_type(4)));
typedef short  bf16x8 __attribute__((ext_vector_type(8)));

union BF8 { unsigned short u[8]; bf16x8 v; };

__device__ __forceinline__ unsigned short f2bf(float f) {   // RNE fp32->bf16
    unsigned u = __float_as_uint(f);
    u += 0x7FFFu + ((u >> 16) & 1u);
    return (unsigned short)(u >> 16);
}
__device__ __forceinline__ float bf2f(unsigned short u) {
    return __uint_as_float(((unsigned)u) << 16);
}

// ---------------- centralized 2-phase grid barrier ------------------------
__device__ __forceinline__ void cbar(unsigned* flags, unsigned* epoch,
                                     int nwg, int wg, unsigned target) {
    __threadfence();              // release prior global writes
    __syncthreads();
    if (threadIdx.x == 0)
        __hip_atomic_store(&flags[wg], target,
                           __ATOMIC_RELAXED, __HIP_MEMORY_SCOPE_AGENT);
    if (wg == 0) {
        for (int i = threadIdx.x; i < nwg; i += blockDim.x)
            while (__hip_atomic_load(&flags[i], __ATOMIC_RELAXED,
                                     __HIP_MEMORY_SCOPE_AGENT) < target)
                __builtin_amdgcn_s_sleep(2);
        __syncthreads();
        if (threadIdx.x == 0)
            __hip_atomic_store(epoch, target,
                               __ATOMIC_RELAXED, __HIP_MEMORY_SCOPE_AGENT);
    }
    if (threadIdx.x == 0)
        while (__hip_atomic_load(epoch, __ATOMIC_RELAXED,
                                 __HIP_MEMORY_SCOPE_AGENT) < target)
            __builtin_amdgcn_s_sleep(2);
    __threadfence();              // acquire
    __syncthreads();
}

__device__ __forceinline__ float red16(float a) {
    a += __shfl_xor(a, 8, 16);
    a += __shfl_xor(a, 4, 16);
    a += __shfl_xor(a, 2, 16);
    a += __shfl_xor(a, 1, 16);
    return a;
}

__device__ __forceinline__ float sigmoidf_(float x) {
    return 1.0f / (1.0f + __expf(-x));
}

// ---------------- emb2 gather -> hi/lo bf16 x0 ----------------------------
__global__ void k_embed(const int* __restrict__ xids,
                        const float* __restrict__ emb2,
                        unsigned short* __restrict__ x0) {
    const int col = blockIdx.x;                 // 96 blocks
    const int tok = xids[col];
    const int tid = threadIdx.x;
    if (tid < 192) {
        float4 v = *(const float4*)(emb2 + (size_t)tok * EMB + tid * 4);
        ushort4 hv, lv;
        hv.x = f2bf(v.x); lv.x = f2bf(v.x - bf2f(hv.x));
        hv.y = f2bf(v.y); lv.y = f2bf(v.y - bf2f(hv.y));
        hv.z = f2bf(v.z); lv.z = f2bf(v.z - bf2f(hv.z));
        hv.w = f2bf(v.w); lv.w = f2bf(v.w - bf2f(hv.w));
        unsigned short* base = x0 + col * XPITCH + (tid >> 2) * 32 + (tid & 3) * 4;
        *(ushort4*)base        = hv;
        *(ushort4*)(base + 16) = lv;
    }
}

// ---------------- A1[t][row] = Wih1@emb1[x_t] + bih1 + bhh1 ---------------
__global__ __launch_bounds__(256) void k_a1(const int* __restrict__ xids,
                                            const float* __restrict__ emb1,
                                            const float* __restrict__ wih,
                                            const float* __restrict__ bih,
                                            const float* __restrict__ bhh,
                                            float* __restrict__ A1) {
    __shared__ float sx[EMB];
    const int tid = threadIdx.x;
    const int l16 = tid & 15;
    const int r16 = tid >> 4;
    const int row = blockIdx.x * 16 + r16;      // 192 blocks x 16 rows
    float w[48];
#pragma unroll
    for (int i = 0; i < 48; ++i)
        w[i] = wih[(size_t)row * EMB + l16 + (i << 4)];
    const float bsum = bih[row] + bhh[row];
    for (int t = 0; t < SEQ; ++t) {
        const int tok = xids[t];
        __syncthreads();
        if (tid < 192) {
            float4 v = *(const float4*)(emb1 + (size_t)tok * EMB + tid * 4);
            *(float4*)(sx + tid * 4) = v;
        }
        __syncthreads();
        float a = 0.f;
#pragma unroll
        for (int i = 0; i < 48; ++i)
            a = fmaf(w[i], sx[l16 + (i << 4)], a);
        a = red16(a);
        if (l16 == 0) A1[t * G4 + row] = a + bsum;
    }
}

// ---------------- fused persistent kernel: 48 conv WGs + 192 LSTM WGs -----
__global__ __launch_bounds__(256, 1) void k_net(
    const float* __restrict__ conv_w, const float* __restrict__ conv_b,
    unsigned short* __restrict__ x0buf, unsigned short* __restrict__ x1buf,
    const float* __restrict__ hstate, const float* __restrict__ cstate,
    const float* __restrict__ wih, const float* __restrict__ whh,
    const float* __restrict__ bih, const float* __restrict__ bhh,
    const float* __restrict__ A1,
    float* __restrict__ h1buf, float* __restrict__ h2buf,
    unsigned* __restrict__ cflags, unsigned* __restrict__ cepoch,
    unsigned* __restrict__ lflags, unsigned* __restrict__ lepoch,
    float* __restrict__ dout) {

    __shared__ __align__(16) unsigned short xs_hi[97 * CKP];   // 51216 B
    __shared__ __align__(16) unsigned short xs_lo[97 * CKP];   // 51216 B
    __shared__ float part[4 * 16 * 96];                        // 24576 B
    __shared__ float hx[EMB], hb2[EMB];
    __shared__ float g1s[16], g2s[16], c1s[4], c2s[4];

    const int tid = threadIdx.x;

    if (blockIdx.x < CONV_WG) {
        // ================= conv path: 16-row slab, split-bf16 MFMA ========
        const int wv = tid >> 6;           // wave 0..3 (K-split)
        const int ln = tid & 63;
        const int lj = ln & 15;            // A-row / B-col lane index
        const int lg = ln >> 4;            // k-group 0..3
        const int bI = blockIdx.x;
        const int r0 = bI * 16;

        for (int lay = 0; lay < NLAYER; ++lay) {
            const int ncols = NLAYER - lay;                // cone pruning
            const int scols = (ncols + 1 < 96) ? ncols + 1 : 96;
            const int nts   = (ncols + 15) >> 4;
            const unsigned short* src = (lay & 1) ? x1buf : x0buf;
            unsigned short*       dst = (lay & 1) ? x0buf : x1buf;
            const float* wsl = conv_w + (size_t)lay * (EMB * EMB * 2)
                                      + (size_t)(r0 + lj) * (EMB * 2);

            f32x4 acc[6];
#pragma unroll
            for (int n = 0; n < 6; ++n) acc[n] = (f32x4)0.f;

            for (int ch = 0; ch < 3; ++ch) {
                // weight loads first (latency hides under staging+sync)
                float4 aw[2][4];
#pragma unroll
                for (int s = 0; s < 2; ++s) {
                    const int K0 = (ch * 8 + wv * 2 + s) * 32;
                    const float4* ap =
                        (const float4*)(wsl + (size_t)(K0 + lg * 8) * 2);
#pragma unroll
                    for (int j = 0; j < 4; ++j) aw[s][j] = ap[j];
                }
                // stage x hi/lo chunk (256 k) into LDS
#pragma unroll
                for (int j = 0; j < 12; ++j) {
                    const int u = tid + j * 256;       // < 3072
                    const int c = u >> 5, q = u & 31;
                    if (c < scols) {
                        const int k = ch * 256 + q * 8;
                        const unsigned short* sp =
                            src + c * XPITCH + ((k >> 4) << 5) + (k & 15);
                        bf16x8 vh = *(const bf16x8*)sp;
                        bf16x8 vl = *(const bf16x8*)(sp + 16);
                        *(bf16x8*)(xs_hi + c * CKP + q * 8) = vh;
                        *(bf16x8*)(xs_lo + c * CKP + q * 8) = vl;
                    }
                }
                __syncthreads();
#pragma unroll
                for (int s = 0; s < 2; ++s) {
                    const int klocal = (wv * 2 + s) * 32;
                    BF8 a0h, a0l, a1h, a1l;
#pragma unroll
                    for (int d = 0; d < 8; ++d) {
                        const float4 f = aw[s][d >> 1];
                        const float w0 = (d & 1) ? f.z : f.x;
                        const float w1 = (d & 1) ? f.w : f.y;
                        const unsigned short h0 = f2bf(w0);
                        const unsigned short h1 = f2bf(w1);
                        a0h.u[d] = h0; a0l.u[d] = f2bf(w0 - bf2f(h0));
                        a1h.u[d] = h1; a1l.u[d] = f2bf(w1 - bf2f(h1));
                    }
#pragma unroll
                    for (int nt = 0; nt < 6; ++nt) if (nt < nts) {
                        const int co = (nt * 16 + lj) * CKP + klocal + lg * 8;
                        bf16x8 bh0 = *(const bf16x8*)(xs_hi + co);
                        bf16x8 bl0 = *(const bf16x8*)(xs_lo + co);
                        bf16x8 bh1 = *(const bf16x8*)(xs_hi + co + CKP);
                        bf16x8 bl1 = *(const bf16x8*)(xs_lo + co + CKP);
                        acc[nt] = __builtin_amdgcn_mfma_f32_16x16x32_bf16(
                                      a0h.v, bh0, acc[nt], 0, 0, 0);
                        acc[nt] = __builtin_amdgcn_mfma_f32_16x16x32_bf16(
                                      a0h.v, bl0, acc[nt], 0, 0, 0);
                        acc[nt] = __builtin_amdgcn_mfma_f32_16x16x32_bf16(
                                      a0l.v, bh0, acc[nt], 0, 0, 0);
                        acc[nt] = __builtin_amdgcn_mfma_f32_16x16x32_bf16(
                                      a1h.v, bh1, acc[nt], 0, 0, 0);
                        acc[nt] = __builtin_amdgcn_mfma_f32_16x16x32_bf16(
                                      a1h.v, bl1, acc[nt], 0, 0, 0);
                        acc[nt] = __builtin_amdgcn_mfma_f32_16x16x32_bf16(
                                      a1l.v, bh1, acc[nt], 0, 0, 0);
                    }
                }
                __syncthreads();                       // xs consumed
            }

            // K-split reduction across 4 waves
#pragma unroll
            for (int nt = 0; nt < 6; ++nt) if (nt < nts)
                *(f32x4*)&part[wv * 1536 + (nt * 16 + lj) * 16 + lg * 4] = acc[nt];
            __syncthreads();
#pragma unroll
            for (int j = 0; j < 6; ++j) {
                const int o = tid + j * 256;           // o = c*16 + i
                const int c = o >> 4, i = o & 15;
                if (c < ncols) {
                    float s = part[o] + part[1536 + o] + part[3072 + o]
                            + part[4608 + o] + conv_b[lay * EMB + r0 + i];
                    s = fmaxf(s, 0.f);
                    const unsigned short sh = f2bf(s);
                    const unsigned short sl = f2bf(s - bf2f(sh));
                    dst[c * XPITCH + bI * 32 + i]      = sh;
                    dst[c * XPITCH + bI * 32 + 16 + i] = sl;
                    if (lay == NLAYER - 1 && c == 0)   // model2out (fp32)
                        dout[3074 + r0 + i] = s;
                }
            }
            if (lay + 1 < NLAYER)
                cbar(cflags, cepoch, CONV_WG, bI, (unsigned)(lay + 1));
        }
    } else {
        // ================= LSTM path: 97 ticks, skewed layers =============
        const int wg   = blockIdx.x - CONV_WG;    // 0..191
        const int l16  = tid & 15;
        const int r16  = tid >> 4;
        const int gate = r16 >> 2;
        const int jl   = r16 & 3;
        const int j0   = wg * 4;
        const int grow = gate * EMB + j0 + jl;

        float wh1r[48], wi2r[48], wh2r[48];
        const float* whh1 = whh;
        const float* wih2 = wih + (size_t)G4 * EMB;
        const float* whh2 = whh + (size_t)G4 * EMB;
#pragma unroll
        for (int i = 0; i < 48; ++i) {
            const int k = l16 + (i << 4);
            wh1r[i] = whh1[(size_t)grow * EMB + k];
            wi2r[i] = wih2[(size_t)grow * EMB + k];
            wh2r[i] = whh2[(size_t)grow * EMB + k];
        }
        const float b2 = bih[G4 + grow] + bhh[G4 + grow];

        if (tid < 4)      c1s[tid]     = cstate[j0 + tid];
        else if (tid < 8) c2s[tid - 4] = cstate[EMB + j0 + (tid - 4)];
        __syncthreads();

        for (int T = 0; T <= SEQ; ++T) {
            if (tid < 192) {
                float4 hv = (T == 0)
                    ? *(const float4*)(hstate + tid * 4)
                    : *(const float4*)(h1buf + (T - 1) * EMB + tid * 4);
                float4 h2v = make_float4(0.f, 0.f, 0.f, 0.f);
                if (T >= 1)
                    h2v = (T == 1)
                        ? *(const float4*)(hstate + EMB + tid * 4)
                        : *(const float4*)(h2buf + (T - 2) * EMB + tid * 4);
                *(float4*)(hx + tid * 4)  = hv;
                *(float4*)(hb2 + tid * 4) = h2v;
            }
            __syncthreads();

            if (T < SEQ) {           // layer 1, step T
                float a = 0.f;
#pragma unroll
                for (int i = 0; i < 48; ++i)
                    a = fmaf(wh1r[i], hx[l16 + (i << 4)], a);
                a = red16(a);
                if (l16 == 0) g1s[r16] = a + A1[T * G4 + grow];
            }
            if (T >= 1) {            // layer 2, step T-1
                float b = 0.f;
#pragma unroll
                for (int i = 0; i < 48; ++i)
                    b = fmaf(wi2r[i], hx[l16 + (i << 4)], b);
#pragma unroll
                for (int i = 0; i < 48; ++i)
                    b = fmaf(wh2r[i], hb2[l16 + (i << 4)], b);
                b = red16(b);
                if (l16 == 0) g2s[r16] = b + b2;
            }
            __syncthreads();

            if (tid < 4 && T < SEQ) {
                const int j = tid;
                const float i_ = sigmoidf_(g1s[j]);
                const float f_ = sigmoidf_(g1s[4 + j]);
                const float g_ = tanhf(g1s[8 + j]);
                const float o_ = sigmoidf_(g1s[12 + j]);
                const float c  = f_ * c1s[j] + i_ * g_;
                c1s[j] = c;
                const float h = o_ * tanhf(c);
                __hip_atomic_store(&h1buf[T * EMB + j0 + j], h,
                                   __ATOMIC_RELAXED, __HIP_MEMORY_SCOPE_AGENT);
                if (T == SEQ - 1) {
                    dout[1 + j0 + j]    = h;   // h[0]
                    dout[1537 + j0 + j] = c;   // c[0]
                }
            } else if (tid >= 4 && tid < 8 && T >= 1) {
                const int j = tid - 4;
                const int s = T - 1;
                const float i_ = sigmoidf_(g2s[j]);
                const float f_ = sigmoidf_(g2s[4 + j]);
                const float g_ = tanhf(g2s[8 + j]);
                const float o_ = sigmoidf_(g2s[12 + j]);
                const float c  = f_ * c2s[j] + i_ * g_;
                c2s[j] = c;
                const float h = o_ * tanhf(c);
                __hip_atomic_store(&h2buf[s * EMB + j0 + j], h,
                                   __ATOMIC_RELAXED, __HIP_MEMORY_SCOPE_AGENT);
                if (s == SEQ - 1) {
                    dout[1 + EMB + j0 + j]    = h;   // h[1]
                    dout[1537 + EMB + j0 + j] = c;   // c[1]
                }
            }
            if (T < SEQ)
                cbar(lflags, lepoch, LSTM_WG, wg, (unsigned)(T + 1));
        }
    }
}

// ---------------- deterministic scalar epilogue ---------------------------
__global__ void k_final(const float* __restrict__ pred_w,
                        const float* __restrict__ pred_b,
                        const float* __restrict__ m2w,
                        const float* __restrict__ m2b,
                        const float* __restrict__ prev,
                        float* __restrict__ dout) {
    __shared__ float red[256];
    const int tid = threadIdx.x;
    float p1 = 0.f;
    for (int idx = tid; idx < 2 * EMB; idx += 256) {
        const int l = idx / EMB;
        const int j = idx - l * EMB;
        p1 += dout[1537 + idx] * pred_w[j * 2 + l];   // feat = c.T interleave
    }
    float p2 = 0.f;
    for (int e = tid; e < EMB; e += 256)
        p2 += dout[3074 + e] * m2w[2 * e] + prev[e] * m2w[2 * e + 1];

    red[tid] = p1;
    __syncthreads();
    for (int s = 128; s > 0; s >>= 1) {
        if (tid < s) red[tid] += red[tid + s];
        __syncthreads();
    }
    if (tid == 0) dout[0] = red[0] + pred_b[0];
    __syncthreads();
    red[tid] = p2;
    __syncthreads();
    for (int s = 128; s > 0; s >>= 1) {
        if (tid < s) red[tid] += red[tid + s];
        __syncthreads();
    }
    if (tid == 0) dout[3073] = red[0] + m2b[0];
}

extern "C" void kernel_launch(void* const* d_in, const int* in_sizes, int n_in,
                              void* d_out, int out_size, void* d_ws, size_t ws_size,
                              hipStream_t stream) {
    const int*   x      = (const int*)d_in[0];
    const float* hstate = (const float*)d_in[1];
    const float* cstate = (const float*)d_in[2];
    const float* prev   = (const float*)d_in[3];
    const float* emb1   = (const float*)d_in[4];
    const float* emb2   = (const float*)d_in[5];
    const float* wih    = (const float*)d_in[6];
    const float* whh    = (const float*)d_in[7];
    const float* bih    = (const float*)d_in[8];
    const float* bhh    = (const float*)d_in[9];
    const float* predw  = (const float*)d_in[10];
    const float* predb  = (const float*)d_in[11];
    const float* convw  = (const float*)d_in[12];
    const float* convb  = (const float*)d_in[13];
    const float* m2w    = (const float*)d_in[14];
    const float* m2b    = (const float*)d_in[15];
    float* out = (float*)d_out;

    unsigned* wsw = (unsigned*)d_ws;
    unsigned* cflags = wsw;            // [0..48)
    unsigned* cepoch = wsw + 64;
    unsigned* lflags = wsw + 128;      // [128..320)
    unsigned* lepoch = wsw + 384;
    float* base  = (float*)d_ws + 1024;
    float* A1    = base;                               // 96*3072 f32
    float* h1buf = A1 + SEQ * G4;                      // 96*768 f32
    float* h2buf = h1buf + SEQ * EMB;                  // 96*768 f32
    unsigned short* x0buf = (unsigned short*)(h2buf + SEQ * EMB); // 96*1536 u16
    unsigned short* x1buf = x0buf + SEQ * XPITCH;                 // 96*1536 u16

    hipMemsetAsync(d_ws, 0, 4096, stream);                   // flags + epochs
    hipMemsetAsync(d_out, 0, out_size * sizeof(float), stream);

    k_embed<<<96, 256, 0, stream>>>(x, emb2, x0buf);
    k_a1<<<192, 256, 0, stream>>>(x, emb1, wih, bih, bhh, A1);
    k_net<<<CONV_WG + LSTM_WG, 256, 0, stream>>>(
        convw, convb, x0buf, x1buf,
        hstate, cstate, wih, whh, bih, bhh, A1, h1buf, h2buf,
        cflags, cepoch, lflags, lepoch, out);
    k_final<<<1, 256, 0, stream>>>(predw, predb, m2w, m2b, prev, out);
}